// Round 2
// baseline (191.773 us; speedup 1.0000x reference)
//
#include <hip/hip_runtime.h>
#include <stdint.h>

// Geometry fixed by the reference: T=2048, B*H=2048 cells.
#define T_STEPS 2048
#define N_CELLS 2048
#define GCELLS  64                      // cells per scan group (= 1 wave)
#define NGROUPS (N_CELLS / GCELLS)      // 32
#define CH      32                      // scan chunk (timesteps)
#define NCH     (T_STEPS / CH)          // 64 chunks
#define BCHUNK  16                      // expand chunk (timesteps)
#define NCHUNK  (T_STEPS / BCHUNK)      // 128
#define FLUX_ELEMS ((size_t)T_STEPS * N_CELLS * 4)

#define AS3 __attribute__((address_space(3)))
#define AS1 __attribute__((address_space(1)))

// State update — bitwise-identical between scan and expand so the boundary
// elements scan writes match expand's recomputation exactly.
//
// Short-chain formulation: since -PET*min(x,y) = max(-PET*x, -PET*y) for
// PET>=0, the S1 update is a max of two affines of S1 (+ clamp at 0):
//   S1' = max3( S1*(a - PET/smax) + P,  S1*a + (P - PET),  0 )
// Critical chain per step: fma -> max3 (2 dependent ops; a_c and P-PET are
// off-chain precomputes). S2' = b*S2 + k2*S1 never needs the 0-clamp:
// all terms are >= +0 and (+0)+(+0) = +0, so fmaxf(.,0) is bitwise identity.
__device__ __forceinline__ void step_state(float& S1, float& S2,
                                           float P, float PET,
                                           float inv_smax, float a, float b,
                                           float k2) {
    float a_c  = fmaf(-PET, inv_smax, a);        // off critical chain
    float PmP  = P - PET;                        // off critical chain
    float t1   = fmaf(S1, a_c, P);
    float t2   = fmaf(S1, a, PmP);
    float S1n  = fmaxf(fmaxf(t1, t2), 0.0f);     // -> v_max3_f32
    float perc = k2 * S1;
    S2 = fmaf(S2, b, perc);                      // clamp provably identity
    S1 = S1n;
}

// ---------------- Pass A: serial scan, chunked counted-vmcnt pipeline -------
// 32 blocks x 64 threads (ONE wave each). Forcings staged global->LDS in
// 32-step chunks (16 x 1KB global_load_lds = 16 KB = CH*32 float4 per chunk),
// 4 rotating 16KB buffers, 3 chunks prefetched ahead. Counted s_waitcnt
// vmcnt(32) retires exactly the chunk being entered (the newest 32 VMEM ops
// are the two younger chunks' DMAs; pending boundary stores are interleaved
// OLDER than the newest chunk, so they only make the wait stricter).
// Max outstanding = 48 DMA + few stores < 63 vmcnt cap.
__global__ void __launch_bounds__(64) hydro_scan(
    const float* __restrict__ forc,        // [T, 2048, 2]
    const float* __restrict__ init_state,  // [2048, 2]
    const float* __restrict__ params,      // [2048, 4]
    float* __restrict__ out)               // fluxes ++ states
{
    __shared__ float4 tile[4][CH * 32];    // 4 x 16 KB  (CH*32 float4 = 16 KB)

    const int g    = blockIdx.x;           // group 0..31
    const int L    = threadIdx.x;          // lane 0..63
    const int cell = g * GCELLS + L;

    float2* out_s = (float2*)(out + FLUX_ELEMS);

    // per-lane global base (float4 units). One t-row = 1024 float4; DMA k
    // covers rows 2k (lanes 0-31) and 2k+1 (lanes 32-63), cols g*32..+31.
    // LDS layout (float2 units): idx2 = tloc*64 + cellloc.
    const float4* gf4 = (const float4*)forc;
    const size_t lane_off = (size_t)(L >> 5) * 1024 + (size_t)g * 32 + (L & 31);

#define ISSUE_DMA(c_) do {                                                     \
        const float4* gp_ = gf4 + (size_t)(c_) * (CH * 1024) + lane_off;       \
        AS3 char* lp_ = (AS3 char*)(void*)tile[(c_) & 3];                      \
        _Pragma("unroll")                                                      \
        for (int k_ = 0; k_ < 16; ++k_)                                        \
            __builtin_amdgcn_global_load_lds(                                  \
                (AS1 const void*)(gp_ + (size_t)k_ * 2048),                    \
                (AS3 void*)(lp_ + (size_t)k_ * 1024), 16, 0, 0);               \
    } while (0)

    // params / init state (independent; retire with the first counted wait)
    const float4 u = ((const float4*)params)[cell];
    float2 s0 = ((const float2*)init_state)[cell];

    ISSUE_DMA(0); ISSUE_DMA(1); ISSUE_DMA(2);          // 48 in flight

    const float smax = 10.0f  + 490.0f * u.x;
    const float k1   = 0.01f  + 0.89f  * u.y;
    const float k2   = 0.001f + 0.199f * u.z;
    const float kb   = 0.001f + 0.099f * u.w;
    const float inv_smax = 1.0f / smax;
    const float a = 1.0f - k1 - k2;
    const float b = 1.0f - kb;
    float S1 = s0.x, S2 = s0.y;

    asm volatile("s_waitcnt vmcnt(32)" ::: "memory");  // chunk 0 resident
    __builtin_amdgcn_sched_barrier(0);

    float2 buf[2][8];
    {
        const float2* tp0 = (const float2*)tile[0];
        #pragma unroll
        for (int j = 0; j < 8; ++j) buf[0][j] = tp0[j * GCELLS + L];
    }

    for (int c = 0; c < NCH; ++c) {
        const float2* tp  = (const float2*)tile[c & 3];
        const float2* tpn = (const float2*)tile[(c + 1) & 3];

        #pragma unroll
        for (int grp = 0; grp < 4; ++grp) {            // 4 x 8 steps per chunk
            const int cur = grp & 1, nxt = cur ^ 1;

            if (grp < 3) {
                // ds-prefetch next group of this chunk (one group ahead:
                // ~100cy of compute covers the ~120cy LDS latency)
                #pragma unroll
                for (int j = 0; j < 8; ++j)
                    buf[nxt][j] = tp[((grp + 1) * 8 + j) * GCELLS + L];
            } else {
                // chunk boundary: top up the DMA pipeline, then wait for
                // chunk c+1 (counted — two younger chunks stay in flight),
                // then ds-prefetch its first group.
                if (c <= NCH - 4) {
                    ISSUE_DMA(c + 3);
                    asm volatile("s_waitcnt vmcnt(32)" ::: "memory");
                } else if (c == NCH - 3) {
                    asm volatile("s_waitcnt vmcnt(16)" ::: "memory");
                } else if (c == NCH - 2) {
                    asm volatile("s_waitcnt vmcnt(0)" ::: "memory");
                }
                __builtin_amdgcn_sched_barrier(0);
                if (c < NCH - 1) {
                    #pragma unroll
                    for (int j = 0; j < 8; ++j)
                        buf[nxt][j] = tpn[j * GCELLS + L];
                }
            }

            #pragma unroll
            for (int j = 0; j < 8; ++j)
                step_state(S1, S2, buf[cur][j].x, buf[cur][j].y,
                           inv_smax, a, b, k2);

            // boundary after step t = c*32+grp*8+7; (t+1)%16==0 <=> grp odd.
            // Skip t=2047 (no chunk reads it).
            if ((grp & 1) == 1 && !(c == NCH - 1 && grp == 3)) {
                int t = c * CH + grp * 8 + 7;
                out_s[(size_t)t * N_CELLS + cell] = make_float2(S1, S2);
            }
        }
    }
#undef ISSUE_DMA
}

// ---------------- Pass B: parallel chunk re-scan; writes everything ---------
// 1024 blocks x 256 threads = 4096 independent waves (16 waves/CU).
// wave = (chunk c, group g): preload ALL 16 forcings into registers (fully
// in flight), read boundary state, recompute 16 steps bitwise-identically
// to the scan, write fluxes + states.
__global__ void __launch_bounds__(256) hydro_expand(
    const float* __restrict__ forc,
    const float* __restrict__ init_state,
    const float* __restrict__ params,
    float* __restrict__ out)
{
    const int blk  = blockIdx.x;
    const int wave = threadIdx.x >> 6;
    const int L    = threadIdx.x & 63;
    const int c    = blk >> 3;                 // chunk 0..127
    const int g    = (blk & 7) * 4 + wave;     // group 0..31
    const int cell = g * GCELLS + L;
    const int t0   = c * BCHUNK;

    float4* out_f = (float4*)out;
    float2* out_s = (float2*)(out + FLUX_ELEMS);
    const float2* fp = (const float2*)forc;
    size_t idx = (size_t)t0 * N_CELLS + cell;

    // all 16 forcing loads in flight before any dependent use
    float2 fb[BCHUNK];
    #pragma unroll
    for (int j = 0; j < BCHUNK; ++j) fb[j] = fp[idx + (size_t)j * N_CELLS];

    const float4 u = ((const float4*)params)[cell];
    float2 sp = (c == 0) ? ((const float2*)init_state)[cell]
                         : out_s[(size_t)(t0 - 1) * N_CELLS + cell];

    const float smax = 10.0f  + 490.0f * u.x;
    const float k1   = 0.01f  + 0.89f  * u.y;
    const float k2   = 0.001f + 0.199f * u.z;
    const float kb   = 0.001f + 0.099f * u.w;
    const float inv_smax = 1.0f / smax;
    const float a = 1.0f - k1 - k2;
    const float b = 1.0f - kb;
    float S1 = sp.x, S2 = sp.y;

    #pragma unroll
    for (int j = 0; j < BCHUNK; ++j) {
        float P = fb[j].x, PET = fb[j].y;
        // fluxes (outputs only; tolerance-checked vs reference)
        float ratio = fminf(S1 * inv_smax, 1.0f);
        float et    = PET * ratio;
        float q1    = k1 * S1;
        float perc  = k2 * S1;
        float qb    = kb * S2;
        // state update — identical expression to the scan (bitwise)
        float S1s = S1, S2s = S2;
        step_state(S1s, S2s, P, PET, inv_smax, a, b, k2);
        size_t o = idx + (size_t)j * N_CELLS;
        out_f[o] = make_float4(et, q1, perc, qb);
        out_s[o] = make_float2(S1s, S2s);
        S1 = S1s; S2 = S2s;
    }
}

extern "C" void kernel_launch(void* const* d_in, const int* in_sizes, int n_in,
                              void* d_out, int out_size, void* d_ws, size_t ws_size,
                              hipStream_t stream) {
    const float* forc = (const float*)d_in[0];
    const float* st0  = (const float*)d_in[1];
    const float* prm  = (const float*)d_in[2];
    float* out  = (float*)d_out;

    hipLaunchKernelGGL(hydro_scan, dim3(NGROUPS), dim3(GCELLS), 0, stream,
                       forc, st0, prm, out);
    hipLaunchKernelGGL(hydro_expand, dim3(NCHUNK * NGROUPS / 4), dim3(256), 0, stream,
                       forc, st0, prm, out);
}